// Round 5
// baseline (1865.022 us; speedup 1.0000x reference)
//
#include <hip/hip_runtime.h>

// ---------------------------------------------------------------------------
// AppUsageFEDformer forward on MI355X (gfx950).
// embed -> 2x [Wq gemm(->qT bf16) -> DFT-GEMM -> mix -> iDFT-GEMM ->
//              Wo gemm(+res) -> decomp -> conv1(relu) -> conv2(+res) -> decomp]
//          -> layernorm(+L-mean sub) -> last-token concat -> proj gemm.
// R4->R5: GEMM K-loop was latency-bound (MfmaUtil 10%, 0 conflicts, 19% HBM:
// 16 MFMAs per barrier vs ~200-900cyc drain).  New GEMM: NO LDS, NO barriers
// -- MFMA fragments are contiguous 16B chunks of A/B rows, loaded straight
// into registers, 2-deep register double-buffer.  Waves drift independently;
// occupancy + ILP hide L2 latency.  XCD swizzle (bid&7 -> bm band) kills the
// 8x A-tile cross-XCD over-fetch (FETCH 75.8MB -> ~26MB on conv1).
// k_embed vectorized float4/ushort4.
// ---------------------------------------------------------------------------

typedef unsigned short u16;
typedef float f32x4 __attribute__((ext_vector_type(4)));
typedef __bf16 bf16x8 __attribute__((ext_vector_type(8)));

__device__ __forceinline__ u16 f2b(float f) {
  unsigned u = __float_as_uint(f);
  return (u16)((u + 0x7FFFu + ((u >> 16) & 1u)) >> 16);
}

// ---------------- bf16 MFMA GEMM:  C = A(MxK) * B(NxK)^T (+bias)(+res)(relu)
// Register-direct: per lane, fragment (mi) of A is the 16B chunk
// A[bm*128+wm+mi*16+(lane&15)][kt*32+(lane>>4)*8 ..+8] -- loaded global->VGPR,
// no LDS, no __syncthreads.  2-deep register double-buffer.  Optional batch
// (blockIdx.z) and transposed store.  SWZ: 1D grid, xcd=bid&7 gets a
// contiguous bm band (requires nbm%8==0, grid=nbn*nbm).
template<bool BIAS, bool RELU, bool RES, bool OUTBF16, bool GUARD, bool TRANS,
         bool SWZ>
__global__ __launch_bounds__(256, 3)
void k_gemm(const u16* __restrict__ A, const u16* __restrict__ B,
            const float* __restrict__ bias, const float* __restrict__ res,
            float* __restrict__ Cf, u16* __restrict__ Cb,
            int M, int N, int K,
            long zA, long zB, long zC, int nbn, int nbm)
{
  const int tid = threadIdx.x;
  const int wave = tid >> 6, lane = tid & 63;
  int bn, bm;
  if (SWZ) {
    int bid = blockIdx.x;
    int xcd = bid & 7, loc = bid >> 3;
    bn = loc % nbn;
    bm = xcd * (nbm >> 3) + loc / nbn;
  } else {
    bn = blockIdx.x;
    bm = blockIdx.y;
  }
  const int bz = blockIdx.z;
  const int wm = (wave >> 1) * 64, wn = (wave & 1) * 64;
  const int r = lane & 15, qd = lane >> 4;

  A += (size_t)bz * zA;
  B += (size_t)bz * zB;

  const u16* pA[4];
  const u16* pB[4];
#pragma unroll
  for (int mi = 0; mi < 4; ++mi) {
    int row = bm * 128 + wm + mi * 16 + r;
    if (GUARD) row = row < M ? row : M - 1;
    pA[mi] = A + (size_t)row * K + qd * 8;
  }
#pragma unroll
  for (int ni = 0; ni < 4; ++ni) {
    int row = bn * 128 + wn + ni * 16 + r;
    if (GUARD) row = row < N ? row : N - 1;
    pB[ni] = B + (size_t)row * K + qd * 8;
  }

  f32x4 acc[4][4];
  const f32x4 z = {0.f, 0.f, 0.f, 0.f};
#pragma unroll
  for (int i = 0; i < 4; ++i)
#pragma unroll
    for (int j = 0; j < 4; ++j) acc[i][j] = z;

  const int nk = K >> 5;
  bf16x8 a0[4], b0[4], a1[4], b1[4];

#pragma unroll
  for (int i = 0; i < 4; ++i) {
    a0[i] = *(const bf16x8*)(pA[i]);
    b0[i] = *(const bf16x8*)(pB[i]);
  }
  for (int kt = 0; kt < nk; kt += 2) {
    if (kt + 1 < nk) {
#pragma unroll
      for (int i = 0; i < 4; ++i) {
        a1[i] = *(const bf16x8*)(pA[i] + (kt + 1) * 32);
        b1[i] = *(const bf16x8*)(pB[i] + (kt + 1) * 32);
      }
    }
#pragma unroll
    for (int mi = 0; mi < 4; ++mi)
#pragma unroll
      for (int ni = 0; ni < 4; ++ni)
        acc[mi][ni] = __builtin_amdgcn_mfma_f32_16x16x32_bf16(
            a0[mi], b0[ni], acc[mi][ni], 0, 0, 0);
    if (kt + 2 < nk) {
#pragma unroll
      for (int i = 0; i < 4; ++i) {
        a0[i] = *(const bf16x8*)(pA[i] + (kt + 2) * 32);
        b0[i] = *(const bf16x8*)(pB[i] + (kt + 2) * 32);
      }
    }
    if (kt + 1 < nk) {
#pragma unroll
      for (int mi = 0; mi < 4; ++mi)
#pragma unroll
        for (int ni = 0; ni < 4; ++ni)
          acc[mi][ni] = __builtin_amdgcn_mfma_f32_16x16x32_bf16(
              a1[mi], b1[ni], acc[mi][ni], 0, 0, 0);
    }
  }

  if (Cf) Cf += (size_t)bz * zC;
  if (Cb) Cb += (size_t)bz * zC;
#pragma unroll
  for (int mi = 0; mi < 4; ++mi) {
#pragma unroll
    for (int ni = 0; ni < 4; ++ni) {
#pragma unroll
      for (int e = 0; e < 4; ++e) {
        int gm = bm * 128 + wm + mi * 16 + qd * 4 + e;  // C/D: row=quad*4+reg
        int gn = bn * 128 + wn + ni * 16 + r;           //       col=lane&15
        if (GUARD && (gm >= M || gn >= N)) continue;
        float v = acc[mi][ni][e];
        if (BIAS) v += bias[gn];
        if (RES)  v += res[(size_t)gm * N + gn];
        if (RELU) v = v > 0.f ? v : 0.f;
        size_t oi = TRANS ? ((size_t)gn * M + gm) : ((size_t)gm * N + gn);
        if (OUTBF16) Cb[oi] = f2b(v);
        else         Cf[oi] = v;
      }
    }
  }
}

// ---------------- misc small kernels ----------------
// dftB [64][512] bf16 B-operand: row m<32 = cos(2pi m l/512); row 32+m =
// -sin(2pi m l/512)  (=> C = Re / Im of rfft).
// Binv [l][64] bf16 inverse-DFT B-operand:
//   m<32:  (m==0?1:2)/512 * cos(2pi m l/512)
//   m>=32: -(2/512) * sin(2pi (m-32) l/512)   (col 32 == 0 -> Im0 dropped)
__global__ void k_basis(u16* __restrict__ dftB, u16* __restrict__ Binv)
{
  int id = blockIdx.x * 256 + threadIdx.x;  // 32768
  if (id >= 32768) return;
  {
    int m = id >> 9, l = id & 511;
    int mm = m & 31;
    float ang = (float)((l * mm) & 511) * (6.283185307179586f / 512.f);
    float s, c;
    __sincosf(ang, &s, &c);
    dftB[id] = f2b(m < 32 ? c : -s);
  }
  {
    int l = id >> 6, m = id & 63;
    int mm = m & 31;
    float ang = (float)((l * mm) & 511) * (6.283185307179586f / 512.f);
    float s, c;
    __sincosf(ang, &s, &c);
    float v;
    if (m < 32) v = (m == 0 ? 1.f : 2.f) * (1.f / 512.f) * c;
    else        v = (mm == 0 ? 0.f : (-2.f / 512.f) * s);
    Binv[id] = f2b(v);
  }
}

__global__ void k_convert(const float* __restrict__ in, u16* __restrict__ out, int n)
{
  int id = blockIdx.x * 256 + threadIdx.x;
  if (id < n) out[id] = f2b(in[id]);
}

__global__ void k_convproj(const float* __restrict__ w, u16* __restrict__ o)
{
  int id = blockIdx.x * 256 + threadIdx.x;  // 10000*544
  if (id >= 10000 * 544) return;
  int n = id / 544, k = id % 544;
  o[id] = f2b(k < 536 ? w[(size_t)n * 536 + k] : 0.f);
}

__global__ void k_embed(const int* __restrict__ xapp, const float* __restrict__ xtime,
                        const float* __restrict__ emb, const float* __restrict__ tw,
                        const float* __restrict__ tb, float* __restrict__ xf,
                        u16* __restrict__ xb)
{
  int id = blockIdx.x * 256 + threadIdx.x;  // B*L*128 = 4.19M (float4 lanes)
  int j = id & 127, bl = id >> 7;
  float4 e = ((const float4*)emb)[(size_t)xapp[bl] * 128 + j];
  float t = xtime[bl];
  float4 w4 = ((const float4*)tw)[j];
  float4 b4 = ((const float4*)tb)[j];
  float4 v;
  v.x = e.x + t * w4.x + b4.x;
  v.y = e.y + t * w4.y + b4.y;
  v.z = e.z + t * w4.z + b4.z;
  v.w = e.w + t * w4.w + b4.w;
  ((float4*)xf)[id] = v;
  ushort4 o;
  o.x = f2b(v.x); o.y = f2b(v.y); o.z = f2b(v.z); o.w = f2b(v.w);
  ((ushort4*)xb)[id] = o;
}

// mode mix: coef[b*512 + h*64+o][m] (Re), [32+m] (Im)  -- bf16 A-operand for
// the inverse-DFT GEMM.  out[b,h,o,m] = sum_i xs[b,h,i,m] * (wr+j wi)[h,i,o,m]
__global__ void k_mix(const float* __restrict__ spec, const float* __restrict__ wr,
                      const float* __restrict__ wi, u16* __restrict__ Ab)
{
  __shared__ float swr[64][64], swi[64][64];   // [i][o]
  __shared__ float sre[4][64], sim[4][64];     // [bsub][i]
  int h = blockIdx.x >> 5, m = blockIdx.x & 31, t = threadIdx.x;
  for (int i = t; i < 4096; i += 256) {
    int ii = i >> 6, oo = i & 63;
    size_t idx = ((size_t)((h * 64 + ii) * 64 + oo)) * 32 + m;
    swr[ii][oo] = wr[idx];
    swi[ii][oo] = wi[idx];
  }
  int o = t & 63, bsub = t >> 6;
  for (int b0 = 0; b0 < 64; b0 += 4) {
    __syncthreads();
    int b = b0 + bsub;
    const float* spb = spec + (size_t)b * 32768;
    sre[bsub][o] = spb[m * 512 + h * 64 + o];
    sim[bsub][o] = spb[(32 + m) * 512 + h * 64 + o];
    __syncthreads();
    float aR = 0.f, aI = 0.f;
#pragma unroll 8
    for (int i = 0; i < 64; ++i) {
      float xr = sre[bsub][i], xi = sim[bsub][i];
      float wrv = swr[i][o], wiv = swi[i][o];
      aR += xr * wrv - xi * wiv;
      aI += xr * wiv + xi * wrv;
    }
    size_t row = (size_t)b * 512 + h * 64 + o;
    Ab[row * 64 + m] = f2b(aR);
    Ab[row * 64 + 32 + m] = f2b(aI);
  }
}

// series_decomp: out = x - movavg_25(x) with edge padding; writes fp32 + bf16
__global__ void k_decomp(const float* __restrict__ in, float* __restrict__ outf,
                         u16* __restrict__ outb)
{
  int id = blockIdx.x * 256 + threadIdx.x;  // B*D*2 halves = 65536
  int d = id & 511;
  int half = (id >> 9) & 1;
  int b = id >> 10;
  const float* xb = in + (size_t)b * 262144 + d;
  int l0 = half * 256;
  float sum = 0.f;
#pragma unroll
  for (int j = -12; j <= 12; ++j) {
    int idx = l0 + j;
    idx = idx < 0 ? 0 : idx;
    sum += xb[idx * 512];
  }
#pragma unroll 4
  for (int l = l0; l < l0 + 256; ++l) {
    float xv = xb[l * 512];
    float o = xv - sum * (1.f / 25.f);
    size_t oi = ((size_t)b * 512 + l) * 512 + d;
    outf[oi] = o;
    outb[oi] = f2b(o);
    int ia = l + 13 > 511 ? 511 : l + 13;
    int ir = l - 12 < 0 ? 0 : l - 12;
    sum += xb[ia * 512] - xb[ir * 512];
  }
}

__global__ void k_lnstats(const float* __restrict__ x, float* __restrict__ mu,
                          float* __restrict__ rs)
{
  int row = blockIdx.x;
  const float* xr = x + (size_t)row * 512;
  int t = threadIdx.x;
  float v0 = xr[t], v1 = xr[t + 256];
  float s = v0 + v1, ss = v0 * v0 + v1 * v1;
#pragma unroll
  for (int off = 32; off; off >>= 1) {
    s += __shfl_down(s, off);
    ss += __shfl_down(ss, off);
  }
  __shared__ float as[4], ass[4];
  if ((t & 63) == 0) { as[t >> 6] = s; ass[t >> 6] = ss; }
  __syncthreads();
  if (t == 0) {
    float S = as[0] + as[1] + as[2] + as[3];
    float SS = ass[0] + ass[1] + ass[2] + ass[3];
    float m = S * (1.f / 512.f);
    float var = SS * (1.f / 512.f) - m * m;
    mu[row] = m;
    rs[row] = rsqrtf(var + 1e-5f);
  }
}

// head: cat[b][d] = w_d * (ln_last - mean_l(ln));  norm_b cancels.
__global__ void k_lastcat(const float* __restrict__ x, const float* __restrict__ mu,
                          const float* __restrict__ rs, const float* __restrict__ nw,
                          u16* __restrict__ cat)
{
  int id = blockIdx.x * 256 + threadIdx.x;  // B*D = 32768
  int b = id >> 9, d = id & 511;
  const float* xb = x + (size_t)b * 262144;
  const float* mub = mu + b * 512;
  const float* rsb = rs + b * 512;
  float acc = 0.f;
#pragma unroll 4
  for (int l = 0; l < 512; ++l)
    acc += (xb[l * 512 + d] - mub[l]) * rsb[l];
  float lastv = (xb[511 * 512 + d] - mub[511]) * rsb[511];
  float v = nw[d] * (lastv - acc * (1.f / 512.f));
  cat[b * 544 + d] = f2b(v);
}

__global__ void k_timecat(const float* __restrict__ tv, u16* __restrict__ cat)
{
  int id = blockIdx.x * 256 + threadIdx.x;  // 64*32
  if (id >= 2048) return;
  int b = id >> 5, j = id & 31;
  int pos = 512 + j;
  float v = (pos < 536) ? tv[((size_t)b * 512 + 511) * 24 + (pos - 512)] : 0.f;
  cat[b * 544 + pos] = f2b(v);
}

// ---------------------------------------------------------------------------
extern "C" void kernel_launch(void* const* d_in, const int* in_sizes, int n_in,
                              void* d_out, int out_size, void* d_ws, size_t ws_size,
                              hipStream_t stream)
{
  (void)in_sizes; (void)n_in; (void)out_size; (void)ws_size;
  const int*   x_app  = (const int*)  d_in[0];
  const float* x_time = (const float*)d_in[1];
  const float* tvec   = (const float*)d_in[2];
  // d_in[3] targets: unused by reference output
  const float* emb    = (const float*)d_in[4];
  const float* time_w = (const float*)d_in[5];
  const float* time_b = (const float*)d_in[6];
  const float* Wq     = (const float*)d_in[7];
  const float* bq     = (const float*)d_in[8];
  const float* Wo     = (const float*)d_in[9];
  const float* bo     = (const float*)d_in[10];
  const float* fwr    = (const float*)d_in[11];
  const float* fwi    = (const float*)d_in[12];
  const float* c1     = (const float*)d_in[13];
  const float* c2     = (const float*)d_in[14];
  const float* norm_w = (const float*)d_in[15];
  // d_in[16] norm_b: cancels in (xh - mean_l xh)
  const float* proj_w = (const float*)d_in[17];
  const float* proj_b = (const float*)d_in[18];
  float* out = (float*)d_out;

  char* w = (char*)d_ws;
  auto alloc = [&](size_t bytes) -> char* {
    char* p = w;
    w += (bytes + 255) & ~(size_t)255;
    return p;
  };
  // Workspace budget: 235.7 MB (256MiB cap; R3 overflow post-mortem)
  float* Ax   = (float*)alloc(67108864);          // x fp32 (B,L,D)
  float* Bs   = (float*)alloc(67108864);          // t1/t2 fp32
  u16*   Cb   = (u16*)  alloc(33554432);          // bf16 activation
  u16*   YqT  = (u16*)  alloc(33554432);          // qT bf16 (early) / conv1 out (late)
  float* S1   = (float*)alloc(8388608);           // spec (B,64,D) fp32
  u16*   Coef = (u16*)  alloc(4194304);           // mixed spectrum, GEMM-A bf16
  u16*   wqb  = (u16*)  alloc(2 * 262144 * 2);
  u16*   wob  = (u16*)  alloc(2 * 262144 * 2);
  u16*   c1b  = (u16*)  alloc(2 * 1048576 * 2);
  u16*   c2b  = (u16*)  alloc(2 * 1048576 * 2);
  u16*   pwb  = (u16*)  alloc(10000 * 544 * 2);
  u16*   dftB = (u16*)  alloc(64 * 512 * 2);
  u16*   Binv = (u16*)  alloc(512 * 64 * 2);
  float* muB  = (float*)alloc(131072);
  float* rsB  = (float*)alloc(131072);
  u16*   cat  = (u16*)  alloc(64 * 544 * 2);

  k_basis<<<128, 256, 0, stream>>>(dftB, Binv);
  k_convert<<<2048, 256, 0, stream>>>(Wq, wqb, 524288);
  k_convert<<<2048, 256, 0, stream>>>(Wo, wob, 524288);
  k_convert<<<8192, 256, 0, stream>>>(c1, c1b, 2097152);
  k_convert<<<8192, 256, 0, stream>>>(c2, c2b, 2097152);
  k_convproj<<<21250, 256, 0, stream>>>(proj_w, pwb);
  k_embed<<<16384, 256, 0, stream>>>(x_app, x_time, emb, time_w, time_b, Ax, Cb);

  for (int l = 0; l < 2; ++l) {
    const u16* wq_l = wqb + l * 262144;
    const u16* wo_l = wob + l * 262144;
    const u16* c1_l = c1b + l * 1048576;
    const u16* c2_l = c2b + l * 1048576;
    const float* fwr_l = fwr + (size_t)l * 1048576;
    const float* fwi_l = fwi + (size_t)l * 1048576;

    // qT[b][d][l] = (x @ Wq^T + bq)^T, bf16, batched over b, TRANS store
    k_gemm<true, false, false, true, false, true, false>
        <<<dim3(4, 4, 64), 256, 0, stream>>>(
        Cb, wq_l, bq + l * 512, nullptr, nullptr, YqT, 512, 512, 512,
        262144, 0, 262144, 0, 0);
    // spec[b][m][d] = qT[b] @ dftB^T  (M=512,N=64 pad 128,K=512), TRANS store
    k_gemm<false, false, false, false, true, true, false>
        <<<dim3(1, 4, 64), 256, 0, stream>>>(
        YqT, dftB, nullptr, nullptr, S1, nullptr, 512, 64, 512,
        262144, 0, 32768, 0, 0);
    k_mix<<<256, 256, 0, stream>>>(S1, fwr_l, fwi_l, Coef);
    // inverse DFT as GEMM: Cb[b*512+d][l] = Coef @ Binv^T  (M=32768,N=512,K=64)
    k_gemm<false, false, false, true, false, false, true>
        <<<dim3(1024, 1, 1), 256, 0, stream>>>(
        Coef, Binv, nullptr, nullptr, nullptr, Cb, 32768, 512, 64,
        0, 0, 0, 4, 256);
    // t1 = fourier_reshaped @ Wo^T + bo + x
    k_gemm<true, false, true, false, false, false, true>
        <<<dim3(1024, 1, 1), 256, 0, stream>>>(
        Cb, wo_l, bo + l * 512, Ax, Bs, nullptr, 32768, 512, 512,
        0, 0, 0, 4, 256);
    k_decomp<<<256, 256, 0, stream>>>(Bs, Ax, Cb);  // x1 fp32 + bf16
    for (int ch = 0; ch < 4; ++ch) {
      const size_t eo = (size_t)ch * 8192 * 512;
      // y = relu(x1 @ c1^T) -> bf16
      k_gemm<false, true, false, true, false, false, true>
          <<<dim3(1024, 1, 1), 256, 0, stream>>>(
          Cb + eo, c1_l, nullptr, nullptr, nullptr, YqT, 8192, 2048, 512,
          0, 0, 0, 16, 64);
      // t2 = y @ c2^T + x1
      k_gemm<false, false, true, false, false, false, true>
          <<<dim3(256, 1, 1), 256, 0, stream>>>(
          YqT, c2_l, nullptr, Ax + eo, Bs + eo, nullptr, 8192, 512, 2048,
          0, 0, 0, 4, 64);
    }
    k_decomp<<<256, 256, 0, stream>>>(Bs, Ax, Cb);  // next-layer x fp32 + bf16
  }

  k_lnstats<<<32768, 256, 0, stream>>>(Ax, muB, rsB);
  k_lastcat<<<128, 256, 0, stream>>>(Ax, muB, rsB, norm_w, cat);
  k_timecat<<<8, 256, 0, stream>>>(tvec, cat);
  // score = cat @ proj_w^T + proj_b   (K padded 536->544 with zeros)
  k_gemm<true, false, false, false, true, false, false>
      <<<dim3(79, 1, 1), 256, 0, stream>>>(
      cat, pwb, proj_b, nullptr, out, nullptr, 64, 10000, 544,
      0, 0, 0, 0, 0);
}

// Round 6
// 1165.900 us; speedup vs baseline: 1.5996x; 1.5996x over previous
//
#include <hip/hip_runtime.h>

// ---------------------------------------------------------------------------
// AppUsageFEDformer forward on MI355X (gfx950).
// embed -> 2x [Wq gemm(->qT bf16) -> DFT-GEMM -> mix -> iDFT-GEMM ->
//              Wo gemm(+res) -> decomp -> conv1(relu) -> conv2(+res) -> decomp]
//          -> layernorm(+L-mean sub) -> last-token concat -> proj gemm.
// R5->R6: R5's no-LDS GEMM regressed (scattered 16-row fragment loads).
// New GEMM core: global->VGPR (coalesced, issued 1 iter ahead) -> ds_write ->
// ONE barrier/iter.  No global_load_lds => barrier drains only lgkmcnt
// (ds_write), NOT the in-flight global loads -- the vmcnt(0) drain that
// capped R4 at MfmaUtil 10% is gone.  XOR bank swizzle kept (0 conflicts in
// R4), XCD-swizzled 1D grid kept (FETCH 75.8->54MB in R5), k_embed float4.
// ---------------------------------------------------------------------------

typedef unsigned short u16;
typedef float f32x4 __attribute__((ext_vector_type(4)));
typedef __bf16 bf16x8 __attribute__((ext_vector_type(8)));

__device__ __forceinline__ u16 f2b(float f) {
  unsigned u = __float_as_uint(f);
  return (u16)((u + 0x7FFFu + ((u >> 16) & 1u)) >> 16);
}

// ---------------- bf16 MFMA GEMM:  C = A(MxK) * B(NxK)^T (+bias)(+res)(relu)
// 128x128 tile, BK=32.  Staging: thread t loads 16B of A and B rows
// r0=t>>2, r1=r0+64, logical 16B-group lg=t&3 (fully coalesced: wave covers
// 1KB contiguous), holds them in VGPRs for one iteration, then ds_writes to
// physical group p = lg ^ ((r>>1)&3)  (XOR swizzle; (r0>>1)&3 == (r1>>1)&3).
// Fragment read: physical group qd ^ ((lane>>1)&3)  -> conflict-free.
template<bool BIAS, bool RELU, bool RES, bool OUTBF16, bool GUARD, bool TRANS,
         bool SWZ>
__global__ __launch_bounds__(256, 3)
void k_gemm(const u16* __restrict__ A, const u16* __restrict__ B,
            const float* __restrict__ bias, const float* __restrict__ res,
            float* __restrict__ Cf, u16* __restrict__ Cb,
            int M, int N, int K,
            long zA, long zB, long zC, int nbn, int nbm)
{
  __shared__ __align__(16) u16 sA[2][128 * 32];
  __shared__ __align__(16) u16 sB[2][128 * 32];
  const int tid = threadIdx.x;
  const int wave = tid >> 6, lane = tid & 63;
  int bn, bm;
  if (SWZ) {
    int bid = blockIdx.x;
    int xcd = bid & 7, loc = bid >> 3;
    bn = loc % nbn;
    bm = xcd * (nbm >> 3) + loc / nbn;
  } else {
    bn = blockIdx.x;
    bm = blockIdx.y;
  }
  const int bz = blockIdx.z;
  const int wm = (wave >> 1) * 64, wn = (wave & 1) * 64;

  A += (size_t)bz * zA;
  B += (size_t)bz * zB;

  // ---- staging geometry (per thread: 2 rows of A + 2 rows of B, 16B each)
  const int r0 = tid >> 2;            // row 0..63 (row1 = r0+64)
  const int lg = tid & 3;             // logical 16B group in the 64B k-slice
  const int ps = lg ^ ((r0 >> 1) & 3);  // physical group (same for r0,r0+64)
  int gmA0 = bm * 128 + r0, gmA1 = gmA0 + 64;
  int gnB0 = bn * 128 + r0, gnB1 = gnB0 + 64;
  if (GUARD) {
    gmA0 = gmA0 < M ? gmA0 : M - 1;
    gmA1 = gmA1 < M ? gmA1 : M - 1;
    gnB0 = gnB0 < N ? gnB0 : N - 1;
    gnB1 = gnB1 < N ? gnB1 : N - 1;
  }
  const size_t rb = (size_t)K * 2;
  const char* pa0 = (const char*)A + (size_t)gmA0 * rb + lg * 16;
  const char* pa1 = (const char*)A + (size_t)gmA1 * rb + lg * 16;
  const char* pb0 = (const char*)B + (size_t)gnB0 * rb + lg * 16;
  const char* pb1 = (const char*)B + (size_t)gnB1 * rb + lg * 16;
  const int w0 = r0 * 32 + ps * 8;    // u16 offset in tile; row1 at +2048

  f32x4 acc[4][4];
  const f32x4 z = {0.f, 0.f, 0.f, 0.f};
#pragma unroll
  for (int i = 0; i < 4; ++i)
#pragma unroll
    for (int j = 0; j < 4; ++j) acc[i][j] = z;

  const int r = lane & 15, qd = lane >> 4;
  const int pA = (qd ^ ((lane >> 1) & 3)) * 8;   // fragment physical group
  const int nk = K >> 5;

  uint4 va0, va1, vb0, vb1;           // tile staged in registers
  auto gload = [&](int kt) {
    const size_t ko = (size_t)kt * 64;
    va0 = *(const uint4*)(pa0 + ko);
    va1 = *(const uint4*)(pa1 + ko);
    vb0 = *(const uint4*)(pb0 + ko);
    vb1 = *(const uint4*)(pb1 + ko);
  };

  gload(0);
  int pg = 0;
  for (int kt = 0; kt < nk; ++kt) {
    // commit staged tile kt to LDS (waits vmcnt on va*/vb* only)
    *(uint4*)&sA[pg][w0]        = va0;
    *(uint4*)&sA[pg][w0 + 2048] = va1;
    *(uint4*)&sB[pg][w0]        = vb0;
    *(uint4*)&sB[pg][w0 + 2048] = vb1;
    if (kt + 1 < nk) gload(kt + 1);   // next tile flies during MFMA below
    __syncthreads();                  // drains lgkm (ds_write), not vmcnt
    bf16x8 af[4], bg[4];
#pragma unroll
    for (int mi = 0; mi < 4; ++mi)
      af[mi] = *(const bf16x8*)&sA[pg][(wm + mi * 16 + r) * 32 + pA];
#pragma unroll
    for (int ni = 0; ni < 4; ++ni)
      bg[ni] = *(const bf16x8*)&sB[pg][(wn + ni * 16 + r) * 32 + pA];
#pragma unroll
    for (int mi = 0; mi < 4; ++mi)
#pragma unroll
      for (int ni = 0; ni < 4; ++ni)
        acc[mi][ni] = __builtin_amdgcn_mfma_f32_16x16x32_bf16(
            af[mi], bg[ni], acc[mi][ni], 0, 0, 0);
    pg ^= 1;
  }

  if (Cf) Cf += (size_t)bz * zC;
  if (Cb) Cb += (size_t)bz * zC;
#pragma unroll
  for (int mi = 0; mi < 4; ++mi) {
#pragma unroll
    for (int ni = 0; ni < 4; ++ni) {
#pragma unroll
      for (int e = 0; e < 4; ++e) {
        int gm = bm * 128 + wm + mi * 16 + qd * 4 + e;  // C/D: row=quad*4+reg
        int gn = bn * 128 + wn + ni * 16 + r;           //       col=lane&15
        if (GUARD && (gm >= M || gn >= N)) continue;
        float v = acc[mi][ni][e];
        if (BIAS) v += bias[gn];
        if (RES)  v += res[(size_t)gm * N + gn];
        if (RELU) v = v > 0.f ? v : 0.f;
        size_t oi = TRANS ? ((size_t)gn * M + gm) : ((size_t)gm * N + gn);
        if (OUTBF16) Cb[oi] = f2b(v);
        else         Cf[oi] = v;
      }
    }
  }
}

// ---------------- misc small kernels ----------------
// dftB [64][512] bf16 B-operand: row m<32 = cos(2pi m l/512); row 32+m =
// -sin(2pi m l/512)  (=> C = Re / Im of rfft).
// Binv [l][64] bf16 inverse-DFT B-operand:
//   m<32:  (m==0?1:2)/512 * cos(2pi m l/512)
//   m>=32: -(2/512) * sin(2pi (m-32) l/512)   (col 32 == 0 -> Im0 dropped)
__global__ void k_basis(u16* __restrict__ dftB, u16* __restrict__ Binv)
{
  int id = blockIdx.x * 256 + threadIdx.x;  // 32768
  if (id >= 32768) return;
  {
    int m = id >> 9, l = id & 511;
    int mm = m & 31;
    float ang = (float)((l * mm) & 511) * (6.283185307179586f / 512.f);
    float s, c;
    __sincosf(ang, &s, &c);
    dftB[id] = f2b(m < 32 ? c : -s);
  }
  {
    int l = id >> 6, m = id & 63;
    int mm = m & 31;
    float ang = (float)((l * mm) & 511) * (6.283185307179586f / 512.f);
    float s, c;
    __sincosf(ang, &s, &c);
    float v;
    if (m < 32) v = (m == 0 ? 1.f : 2.f) * (1.f / 512.f) * c;
    else        v = (mm == 0 ? 0.f : (-2.f / 512.f) * s);
    Binv[id] = f2b(v);
  }
}

__global__ void k_convert(const float* __restrict__ in, u16* __restrict__ out, int n)
{
  int id = blockIdx.x * 256 + threadIdx.x;
  if (id < n) out[id] = f2b(in[id]);
}

__global__ void k_convproj(const float* __restrict__ w, u16* __restrict__ o)
{
  int id = blockIdx.x * 256 + threadIdx.x;  // 10000*544
  if (id >= 10000 * 544) return;
  int n = id / 544, k = id % 544;
  o[id] = f2b(k < 536 ? w[(size_t)n * 536 + k] : 0.f);
}

__global__ void k_embed(const int* __restrict__ xapp, const float* __restrict__ xtime,
                        const float* __restrict__ emb, const float* __restrict__ tw,
                        const float* __restrict__ tb, float* __restrict__ xf,
                        u16* __restrict__ xb)
{
  int id = blockIdx.x * 256 + threadIdx.x;  // B*L*128 = 4.19M (float4 lanes)
  int j = id & 127, bl = id >> 7;
  float4 e = ((const float4*)emb)[(size_t)xapp[bl] * 128 + j];
  float t = xtime[bl];
  float4 w4 = ((const float4*)tw)[j];
  float4 b4 = ((const float4*)tb)[j];
  float4 v;
  v.x = e.x + t * w4.x + b4.x;
  v.y = e.y + t * w4.y + b4.y;
  v.z = e.z + t * w4.z + b4.z;
  v.w = e.w + t * w4.w + b4.w;
  ((float4*)xf)[id] = v;
  ushort4 o;
  o.x = f2b(v.x); o.y = f2b(v.y); o.z = f2b(v.z); o.w = f2b(v.w);
  ((ushort4*)xb)[id] = o;
}

// mode mix: coef[b*512 + h*64+o][m] (Re), [32+m] (Im)  -- bf16 A-operand for
// the inverse-DFT GEMM.  out[b,h,o,m] = sum_i xs[b,h,i,m] * (wr+j wi)[h,i,o,m]
__global__ void k_mix(const float* __restrict__ spec, const float* __restrict__ wr,
                      const float* __restrict__ wi, u16* __restrict__ Ab)
{
  __shared__ float swr[64][64], swi[64][64];   // [i][o]
  __shared__ float sre[4][64], sim[4][64];     // [bsub][i]
  int h = blockIdx.x >> 5, m = blockIdx.x & 31, t = threadIdx.x;
  for (int i = t; i < 4096; i += 256) {
    int ii = i >> 6, oo = i & 63;
    size_t idx = ((size_t)((h * 64 + ii) * 64 + oo)) * 32 + m;
    swr[ii][oo] = wr[idx];
    swi[ii][oo] = wi[idx];
  }
  int o = t & 63, bsub = t >> 6;
  for (int b0 = 0; b0 < 64; b0 += 4) {
    __syncthreads();
    int b = b0 + bsub;
    const float* spb = spec + (size_t)b * 32768;
    sre[bsub][o] = spb[m * 512 + h * 64 + o];
    sim[bsub][o] = spb[(32 + m) * 512 + h * 64 + o];
    __syncthreads();
    float aR = 0.f, aI = 0.f;
#pragma unroll 8
    for (int i = 0; i < 64; ++i) {
      float xr = sre[bsub][i], xi = sim[bsub][i];
      float wrv = swr[i][o], wiv = swi[i][o];
      aR += xr * wrv - xi * wiv;
      aI += xr * wiv + xi * wrv;
    }
    size_t row = (size_t)b * 512 + h * 64 + o;
    Ab[row * 64 + m] = f2b(aR);
    Ab[row * 64 + 32 + m] = f2b(aI);
  }
}

// series_decomp: out = x - movavg_25(x) with edge padding; writes fp32 + bf16
__global__ void k_decomp(const float* __restrict__ in, float* __restrict__ outf,
                         u16* __restrict__ outb)
{
  int id = blockIdx.x * 256 + threadIdx.x;  // B*D*2 halves = 65536
  int d = id & 511;
  int half = (id >> 9) & 1;
  int b = id >> 10;
  const float* xb = in + (size_t)b * 262144 + d;
  int l0 = half * 256;
  float sum = 0.f;
#pragma unroll
  for (int j = -12; j <= 12; ++j) {
    int idx = l0 + j;
    idx = idx < 0 ? 0 : idx;
    sum += xb[idx * 512];
  }
#pragma unroll 4
  for (int l = l0; l < l0 + 256; ++l) {
    float xv = xb[l * 512];
    float o = xv - sum * (1.f / 25.f);
    size_t oi = ((size_t)b * 512 + l) * 512 + d;
    outf[oi] = o;
    outb[oi] = f2b(o);
    int ia = l + 13 > 511 ? 511 : l + 13;
    int ir = l - 12 < 0 ? 0 : l - 12;
    sum += xb[ia * 512] - xb[ir * 512];
  }
}

__global__ void k_lnstats(const float* __restrict__ x, float* __restrict__ mu,
                          float* __restrict__ rs)
{
  int row = blockIdx.x;
  const float* xr = x + (size_t)row * 512;
  int t = threadIdx.x;
  float v0 = xr[t], v1 = xr[t + 256];
  float s = v0 + v1, ss = v0 * v0 + v1 * v1;
#pragma unroll
  for (int off = 32; off; off >>= 1) {
    s += __shfl_down(s, off);
    ss += __shfl_down(ss, off);
  }
  __shared__ float as[4], ass[4];
  if ((t & 63) == 0) { as[t >> 6] = s; ass[t >> 6] = ss; }
  __syncthreads();
  if (t == 0) {
    float S = as[0] + as[1] + as[2] + as[3];
    float SS = ass[0] + ass[1] + ass[2] + ass[3];
    float m = S * (1.f / 512.f);
    float var = SS * (1.f / 512.f) - m * m;
    mu[row] = m;
    rs[row] = rsqrtf(var + 1e-5f);
  }
}

// head: cat[b][d] = w_d * (ln_last - mean_l(ln));  norm_b cancels.
__global__ void k_lastcat(const float* __restrict__ x, const float* __restrict__ mu,
                          const float* __restrict__ rs, const float* __restrict__ nw,
                          u16* __restrict__ cat)
{
  int id = blockIdx.x * 256 + threadIdx.x;  // B*D = 32768
  int b = id >> 9, d = id & 511;
  const float* xb = x + (size_t)b * 262144;
  const float* mub = mu + b * 512;
  const float* rsb = rs + b * 512;
  float acc = 0.f;
#pragma unroll 4
  for (int l = 0; l < 512; ++l)
    acc += (xb[l * 512 + d] - mub[l]) * rsb[l];
  float lastv = (xb[511 * 512 + d] - mub[511]) * rsb[511];
  float v = nw[d] * (lastv - acc * (1.f / 512.f));
  cat[b * 544 + d] = f2b(v);
}

__global__ void k_timecat(const float* __restrict__ tv, u16* __restrict__ cat)
{
  int id = blockIdx.x * 256 + threadIdx.x;  // 64*32
  if (id >= 2048) return;
  int b = id >> 5, j = id & 31;
  int pos = 512 + j;
  float v = (pos < 536) ? tv[((size_t)b * 512 + 511) * 24 + (pos - 512)] : 0.f;
  cat[b * 544 + pos] = f2b(v);
}

// ---------------------------------------------------------------------------
extern "C" void kernel_launch(void* const* d_in, const int* in_sizes, int n_in,
                              void* d_out, int out_size, void* d_ws, size_t ws_size,
                              hipStream_t stream)
{
  (void)in_sizes; (void)n_in; (void)out_size; (void)ws_size;
  const int*   x_app  = (const int*)  d_in[0];
  const float* x_time = (const float*)d_in[1];
  const float* tvec   = (const float*)d_in[2];
  // d_in[3] targets: unused by reference output
  const float* emb    = (const float*)d_in[4];
  const float* time_w = (const float*)d_in[5];
  const float* time_b = (const float*)d_in[6];
  const float* Wq     = (const float*)d_in[7];
  const float* bq     = (const float*)d_in[8];
  const float* Wo     = (const float*)d_in[9];
  const float* bo     = (const float*)d_in[10];
  const float* fwr    = (const float*)d_in[11];
  const float* fwi    = (const float*)d_in[12];
  const float* c1     = (const float*)d_in[13];
  const float* c2     = (const float*)d_in[14];
  const float* norm_w = (const float*)d_in[15];
  // d_in[16] norm_b: cancels in (xh - mean_l xh)
  const float* proj_w = (const float*)d_in[17];
  const float* proj_b = (const float*)d_in[18];
  float* out = (float*)d_out;

  char* w = (char*)d_ws;
  auto alloc = [&](size_t bytes) -> char* {
    char* p = w;
    w += (bytes + 255) & ~(size_t)255;
    return p;
  };
  // Workspace budget: 235.7 MB (256MiB cap; R3 overflow post-mortem)
  float* Ax   = (float*)alloc(67108864);          // x fp32 (B,L,D)
  float* Bs   = (float*)alloc(67108864);          // t1/t2 fp32
  u16*   Cb   = (u16*)  alloc(33554432);          // bf16 activation
  u16*   YqT  = (u16*)  alloc(33554432);          // qT bf16 (early) / conv1 out (late)
  float* S1   = (float*)alloc(8388608);           // spec (B,64,D) fp32
  u16*   Coef = (u16*)  alloc(4194304);           // mixed spectrum, GEMM-A bf16
  u16*   wqb  = (u16*)  alloc(2 * 262144 * 2);
  u16*   wob  = (u16*)  alloc(2 * 262144 * 2);
  u16*   c1b  = (u16*)  alloc(2 * 1048576 * 2);
  u16*   c2b  = (u16*)  alloc(2 * 1048576 * 2);
  u16*   pwb  = (u16*)  alloc(10000 * 544 * 2);
  u16*   dftB = (u16*)  alloc(64 * 512 * 2);
  u16*   Binv = (u16*)  alloc(512 * 64 * 2);
  float* muB  = (float*)alloc(131072);
  float* rsB  = (float*)alloc(131072);
  u16*   cat  = (u16*)  alloc(64 * 544 * 2);

  k_basis<<<128, 256, 0, stream>>>(dftB, Binv);
  k_convert<<<2048, 256, 0, stream>>>(Wq, wqb, 524288);
  k_convert<<<2048, 256, 0, stream>>>(Wo, wob, 524288);
  k_convert<<<8192, 256, 0, stream>>>(c1, c1b, 2097152);
  k_convert<<<8192, 256, 0, stream>>>(c2, c2b, 2097152);
  k_convproj<<<21250, 256, 0, stream>>>(proj_w, pwb);
  k_embed<<<16384, 256, 0, stream>>>(x_app, x_time, emb, time_w, time_b, Ax, Cb);

  for (int l = 0; l < 2; ++l) {
    const u16* wq_l = wqb + l * 262144;
    const u16* wo_l = wob + l * 262144;
    const u16* c1_l = c1b + l * 1048576;
    const u16* c2_l = c2b + l * 1048576;
    const float* fwr_l = fwr + (size_t)l * 1048576;
    const float* fwi_l = fwi + (size_t)l * 1048576;

    // qT[b][d][l] = (x @ Wq^T + bq)^T, bf16, batched over b, TRANS store
    k_gemm<true, false, false, true, false, true, false>
        <<<dim3(4, 4, 64), 256, 0, stream>>>(
        Cb, wq_l, bq + l * 512, nullptr, nullptr, YqT, 512, 512, 512,
        262144, 0, 262144, 0, 0);
    // spec[b][m][d] = qT[b] @ dftB^T  (M=512,N=64 pad 128,K=512), TRANS store
    k_gemm<false, false, false, false, true, true, false>
        <<<dim3(1, 4, 64), 256, 0, stream>>>(
        YqT, dftB, nullptr, nullptr, S1, nullptr, 512, 64, 512,
        262144, 0, 32768, 0, 0);
    k_mix<<<256, 256, 0, stream>>>(S1, fwr_l, fwi_l, Coef);
    // inverse DFT as GEMM: Cb[b*512+d][l] = Coef @ Binv^T  (M=32768,N=512,K=64)
    k_gemm<false, false, false, true, false, false, true>
        <<<dim3(1024, 1, 1), 256, 0, stream>>>(
        Coef, Binv, nullptr, nullptr, nullptr, Cb, 32768, 512, 64,
        0, 0, 0, 4, 256);
    // t1 = fourier_reshaped @ Wo^T + bo + x
    k_gemm<true, false, true, false, false, false, true>
        <<<dim3(1024, 1, 1), 256, 0, stream>>>(
        Cb, wo_l, bo + l * 512, Ax, Bs, nullptr, 32768, 512, 512,
        0, 0, 0, 4, 256);
    k_decomp<<<256, 256, 0, stream>>>(Bs, Ax, Cb);  // x1 fp32 + bf16
    for (int ch = 0; ch < 4; ++ch) {
      const size_t eo = (size_t)ch * 8192 * 512;
      // y = relu(x1 @ c1^T) -> bf16
      k_gemm<false, true, false, true, false, false, true>
          <<<dim3(1024, 1, 1), 256, 0, stream>>>(
          Cb + eo, c1_l, nullptr, nullptr, nullptr, YqT, 8192, 2048, 512,
          0, 0, 0, 16, 64);
      // t2 = y @ c2^T + x1
      k_gemm<false, false, true, false, false, false, true>
          <<<dim3(256, 1, 1), 256, 0, stream>>>(
          YqT, c2_l, nullptr, Ax + eo, Bs + eo, nullptr, 8192, 512, 2048,
          0, 0, 0, 4, 64);
    }
    k_decomp<<<256, 256, 0, stream>>>(Bs, Ax, Cb);  // next-layer x fp32 + bf16
  }

  k_lnstats<<<32768, 256, 0, stream>>>(Ax, muB, rsB);
  k_lastcat<<<128, 256, 0, stream>>>(Ax, muB, rsB, norm_w, cat);
  k_timecat<<<8, 256, 0, stream>>>(tvec, cat);
  // score = cat @ proj_w^T + proj_b   (K padded 536->544 with zeros)
  k_gemm<true, false, false, false, true, false, false>
      <<<dim3(79, 1, 1), 256, 0, stream>>>(
      cat, pwb, proj_b, nullptr, out, nullptr, 64, 10000, 544,
      0, 0, 0, 0, 0);
}

// Round 7
// 1117.826 us; speedup vs baseline: 1.6684x; 1.0430x over previous
//
#include <hip/hip_runtime.h>

// ---------------------------------------------------------------------------
// AppUsageFEDformer forward on MI355X (gfx950).
// embed -> 2x [Wq gemm(->qT bf16) -> DFT-GEMM -> mix -> iDFT-GEMM ->
//              Wo gemm(+res) -> decomp -> conv1(relu) -> conv2(+res) -> decomp]
//          -> layernorm(+L-mean sub) -> last-token concat -> proj gemm.
// R6->R7: k_mix was top dispatch (61us x2): uncoalesced 128B-stride weight
// loads (32x line amplification, FETCH 36.9MB) + 1 block/CU.  Fix: one-time
// LDS-tiled weight transpose wrT[(h*32+m)][i][o] (+padded LDS, stride 33),
// k_mix loads 32KB coalesced; grid 256x4 (batch split) -> 4 blocks/CU.
// GEMM core unchanged from R6: global->VGPR -> ds_write double-buffer, one
// barrier/iter (drains lgkm only, not vmcnt), XOR bank swizzle, XCD swizzle.
// ---------------------------------------------------------------------------

typedef unsigned short u16;
typedef float f32x4 __attribute__((ext_vector_type(4)));
typedef __bf16 bf16x8 __attribute__((ext_vector_type(8)));

__device__ __forceinline__ u16 f2b(float f) {
  unsigned u = __float_as_uint(f);
  return (u16)((u + 0x7FFFu + ((u >> 16) & 1u)) >> 16);
}

// ---------------- bf16 MFMA GEMM:  C = A(MxK) * B(NxK)^T (+bias)(+res)(relu)
// 128x128 tile, BK=32.  Staging: thread t loads 16B of A and B rows
// r0=t>>2, r1=r0+64, logical 16B-group lg=t&3 (fully coalesced: wave covers
// 1KB contiguous), holds them in VGPRs for one iteration, then ds_writes to
// physical group p = lg ^ ((r>>1)&3)  (XOR swizzle; (r0>>1)&3 == (r1>>1)&3).
// Fragment read: physical group qd ^ ((lane>>1)&3)  -> conflict-free.
template<bool BIAS, bool RELU, bool RES, bool OUTBF16, bool GUARD, bool TRANS,
         bool SWZ>
__global__ __launch_bounds__(256, 3)
void k_gemm(const u16* __restrict__ A, const u16* __restrict__ B,
            const float* __restrict__ bias, const float* __restrict__ res,
            float* __restrict__ Cf, u16* __restrict__ Cb,
            int M, int N, int K,
            long zA, long zB, long zC, int nbn, int nbm)
{
  __shared__ __align__(16) u16 sA[2][128 * 32];
  __shared__ __align__(16) u16 sB[2][128 * 32];
  const int tid = threadIdx.x;
  const int wave = tid >> 6, lane = tid & 63;
  int bn, bm;
  if (SWZ) {
    int bid = blockIdx.x;
    int xcd = bid & 7, loc = bid >> 3;
    bn = loc % nbn;
    bm = xcd * (nbm >> 3) + loc / nbn;
  } else {
    bn = blockIdx.x;
    bm = blockIdx.y;
  }
  const int bz = blockIdx.z;
  const int wm = (wave >> 1) * 64, wn = (wave & 1) * 64;

  A += (size_t)bz * zA;
  B += (size_t)bz * zB;

  // ---- staging geometry (per thread: 2 rows of A + 2 rows of B, 16B each)
  const int r0 = tid >> 2;            // row 0..63 (row1 = r0+64)
  const int lg = tid & 3;             // logical 16B group in the 64B k-slice
  const int ps = lg ^ ((r0 >> 1) & 3);  // physical group (same for r0,r0+64)
  int gmA0 = bm * 128 + r0, gmA1 = gmA0 + 64;
  int gnB0 = bn * 128 + r0, gnB1 = gnB0 + 64;
  if (GUARD) {
    gmA0 = gmA0 < M ? gmA0 : M - 1;
    gmA1 = gmA1 < M ? gmA1 : M - 1;
    gnB0 = gnB0 < N ? gnB0 : N - 1;
    gnB1 = gnB1 < N ? gnB1 : N - 1;
  }
  const size_t rb = (size_t)K * 2;
  const char* pa0 = (const char*)A + (size_t)gmA0 * rb + lg * 16;
  const char* pa1 = (const char*)A + (size_t)gmA1 * rb + lg * 16;
  const char* pb0 = (const char*)B + (size_t)gnB0 * rb + lg * 16;
  const char* pb1 = (const char*)B + (size_t)gnB1 * rb + lg * 16;
  const int w0 = r0 * 32 + ps * 8;    // u16 offset in tile; row1 at +2048

  f32x4 acc[4][4];
  const f32x4 z = {0.f, 0.f, 0.f, 0.f};
#pragma unroll
  for (int i = 0; i < 4; ++i)
#pragma unroll
    for (int j = 0; j < 4; ++j) acc[i][j] = z;

  const int r = lane & 15, qd = lane >> 4;
  const int pA = (qd ^ ((lane >> 1) & 3)) * 8;   // fragment physical group
  const int nk = K >> 5;

  uint4 va0, va1, vb0, vb1;           // tile staged in registers
  auto gload = [&](int kt) {
    const size_t ko = (size_t)kt * 64;
    va0 = *(const uint4*)(pa0 + ko);
    va1 = *(const uint4*)(pa1 + ko);
    vb0 = *(const uint4*)(pb0 + ko);
    vb1 = *(const uint4*)(pb1 + ko);
  };

  gload(0);
  int pg = 0;
  for (int kt = 0; kt < nk; ++kt) {
    // commit staged tile kt to LDS (waits vmcnt on va*/vb* only)
    *(uint4*)&sA[pg][w0]        = va0;
    *(uint4*)&sA[pg][w0 + 2048] = va1;
    *(uint4*)&sB[pg][w0]        = vb0;
    *(uint4*)&sB[pg][w0 + 2048] = vb1;
    if (kt + 1 < nk) gload(kt + 1);   // next tile flies during MFMA below
    __syncthreads();                  // drains lgkm (ds_write), not vmcnt
    bf16x8 af[4], bg[4];
#pragma unroll
    for (int mi = 0; mi < 4; ++mi)
      af[mi] = *(const bf16x8*)&sA[pg][(wm + mi * 16 + r) * 32 + pA];
#pragma unroll
    for (int ni = 0; ni < 4; ++ni)
      bg[ni] = *(const bf16x8*)&sB[pg][(wn + ni * 16 + r) * 32 + pA];
#pragma unroll
    for (int mi = 0; mi < 4; ++mi)
#pragma unroll
      for (int ni = 0; ni < 4; ++ni)
        acc[mi][ni] = __builtin_amdgcn_mfma_f32_16x16x32_bf16(
            af[mi], bg[ni], acc[mi][ni], 0, 0, 0);
    pg ^= 1;
  }

  if (Cf) Cf += (size_t)bz * zC;
  if (Cb) Cb += (size_t)bz * zC;
#pragma unroll
  for (int mi = 0; mi < 4; ++mi) {
#pragma unroll
    for (int ni = 0; ni < 4; ++ni) {
#pragma unroll
      for (int e = 0; e < 4; ++e) {
        int gm = bm * 128 + wm + mi * 16 + qd * 4 + e;  // C/D: row=quad*4+reg
        int gn = bn * 128 + wn + ni * 16 + r;           //       col=lane&15
        if (GUARD && (gm >= M || gn >= N)) continue;
        float v = acc[mi][ni][e];
        if (BIAS) v += bias[gn];
        if (RES)  v += res[(size_t)gm * N + gn];
        if (RELU) v = v > 0.f ? v : 0.f;
        size_t oi = TRANS ? ((size_t)gn * M + gm) : ((size_t)gm * N + gn);
        if (OUTBF16) Cb[oi] = f2b(v);
        else         Cf[oi] = v;
      }
    }
  }
}

// ---------------- misc small kernels ----------------
// dftB [64][512] bf16 B-operand: row m<32 = cos(2pi m l/512); row 32+m =
// -sin(2pi m l/512)  (=> C = Re / Im of rfft).
// Binv [l][64] bf16 inverse-DFT B-operand:
//   m<32:  (m==0?1:2)/512 * cos(2pi m l/512)
//   m>=32: -(2/512) * sin(2pi (m-32) l/512)   (col 32 == 0 -> Im0 dropped)
__global__ void k_basis(u16* __restrict__ dftB, u16* __restrict__ Binv)
{
  int id = blockIdx.x * 256 + threadIdx.x;  // 32768
  if (id >= 32768) return;
  {
    int m = id >> 9, l = id & 511;
    int mm = m & 31;
    float ang = (float)((l * mm) & 511) * (6.283185307179586f / 512.f);
    float s, c;
    __sincosf(ang, &s, &c);
    dftB[id] = f2b(m < 32 ? c : -s);
  }
  {
    int l = id >> 6, m = id & 63;
    int mm = m & 31;
    float ang = (float)((l * mm) & 511) * (6.283185307179586f / 512.f);
    float s, c;
    __sincosf(ang, &s, &c);
    float v;
    if (m < 32) v = (m == 0 ? 1.f : 2.f) * (1.f / 512.f) * c;
    else        v = (mm == 0 ? 0.f : (-2.f / 512.f) * s);
    Binv[id] = f2b(v);
  }
}

__global__ void k_convert(const float* __restrict__ in, u16* __restrict__ out, int n)
{
  int id = blockIdx.x * 256 + threadIdx.x;
  if (id < n) out[id] = f2b(in[id]);
}

__global__ void k_convproj(const float* __restrict__ w, u16* __restrict__ o)
{
  int id = blockIdx.x * 256 + threadIdx.x;  // 10000*544
  if (id >= 10000 * 544) return;
  int n = id / 544, k = id % 544;
  o[id] = f2b(k < 536 ? w[(size_t)n * 536 + k] : 0.f);
}

// weight transpose for the mode mix: wrT[((l*8+h)*32+m)][i][o] from
// wr[(((l*8+h)*64+i)*64+o)*32+m].  One block per (l,h,i) slab (64x32 floats),
// LDS tile padded to stride 33 (transposed read would otherwise hit one bank
// 64-way).  Both arrays in one kernel.
__global__ void k_transp(const float* __restrict__ wr, const float* __restrict__ wi,
                         float* __restrict__ wrT, float* __restrict__ wiT)
{
  __shared__ float tr[64 * 33], ti[64 * 33];
  int blk = blockIdx.x;            // (l*8+h)*64+i, 1024 blocks
  int t = threadIdx.x;
  int lh = blk >> 6, i = blk & 63;
  const size_t src = (size_t)blk * 2048;   // o*32+m slab
#pragma unroll
  for (int p = 0; p < 8; ++p) {
    int id = p * 256 + t;          // id = o*32+m, coalesced
    int o = id >> 5, m = id & 31;
    tr[o * 33 + m] = wr[src + id];
    ti[o * 33 + m] = wi[src + id];
  }
  __syncthreads();
#pragma unroll
  for (int p = 0; p < 8; ++p) {
    int id = p * 256 + t;          // id = m*64+o
    int m = id >> 6, o = id & 63;
    size_t dst = ((size_t)(lh * 32 + m) * 64 + i) * 64 + o;  // coalesced in o
    wrT[dst] = tr[o * 33 + m];
    wiT[dst] = ti[o * 33 + m];
  }
}

__global__ void k_embed(const int* __restrict__ xapp, const float* __restrict__ xtime,
                        const float* __restrict__ emb, const float* __restrict__ tw,
                        const float* __restrict__ tb, float* __restrict__ xf,
                        u16* __restrict__ xb)
{
  int id = blockIdx.x * 256 + threadIdx.x;  // B*L*128 = 4.19M (float4 lanes)
  int j = id & 127, bl = id >> 7;
  float4 e = ((const float4*)emb)[(size_t)xapp[bl] * 128 + j];
  float t = xtime[bl];
  float4 w4 = ((const float4*)tw)[j];
  float4 b4 = ((const float4*)tb)[j];
  float4 v;
  v.x = e.x + t * w4.x + b4.x;
  v.y = e.y + t * w4.y + b4.y;
  v.z = e.z + t * w4.z + b4.z;
  v.w = e.w + t * w4.w + b4.w;
  ((float4*)xf)[id] = v;
  ushort4 o;
  o.x = f2b(v.x); o.y = f2b(v.y); o.z = f2b(v.z); o.w = f2b(v.w);
  ((ushort4*)xb)[id] = o;
}

// mode mix: coef[b*512 + h*64+o][m] (Re), [32+m] (Im)  -- bf16 A-operand for
// the inverse-DFT GEMM.  out[b,h,o,m] = sum_i xs[b,h,i,m] * (wr+j wi)[h,i,o,m]
// Block (hm, bgroup): weights from wrT (coalesced 32KB), 16 batches/block.
__global__ __launch_bounds__(256)
void k_mix(const float* __restrict__ spec, const float* __restrict__ wrT,
           const float* __restrict__ wiT, u16* __restrict__ Ab)
{
  __shared__ float swr[4096], swi[4096];   // [i*64+o]
  __shared__ float sre[4][64], sim[4][64]; // [bsub][i]
  int hm = blockIdx.x;                     // h*32+m
  int bg = blockIdx.y;                     // 0..3
  int h = hm >> 5, m = hm & 31, t = threadIdx.x;
  const float* wrb = wrT + (size_t)hm * 4096;
  const float* wib = wiT + (size_t)hm * 4096;
#pragma unroll
  for (int p = 0; p < 16; ++p) {
    int id = p * 256 + t;
    swr[id] = wrb[id];
    swi[id] = wib[id];
  }
  int o = t & 63, bsub = t >> 6;
  for (int b0 = 0; b0 < 16; b0 += 4) {
    __syncthreads();
    int b = bg * 16 + b0 + bsub;
    const float* spb = spec + (size_t)b * 32768;
    sre[bsub][o] = spb[m * 512 + h * 64 + o];
    sim[bsub][o] = spb[(32 + m) * 512 + h * 64 + o];
    __syncthreads();
    float aR = 0.f, aI = 0.f;
#pragma unroll 8
    for (int i = 0; i < 64; ++i) {
      float xr = sre[bsub][i], xi = sim[bsub][i];
      float wrv = swr[i * 64 + o], wiv = swi[i * 64 + o];
      aR += xr * wrv - xi * wiv;
      aI += xr * wiv + xi * wrv;
    }
    size_t row = (size_t)b * 512 + h * 64 + o;
    Ab[row * 64 + m] = f2b(aR);
    Ab[row * 64 + 32 + m] = f2b(aI);
  }
}

// series_decomp: out = x - movavg_25(x) with edge padding; writes fp32 + bf16
__global__ void k_decomp(const float* __restrict__ in, float* __restrict__ outf,
                         u16* __restrict__ outb)
{
  int id = blockIdx.x * 256 + threadIdx.x;  // B*D*2 halves = 65536
  int d = id & 511;
  int half = (id >> 9) & 1;
  int b = id >> 10;
  const float* xb = in + (size_t)b * 262144 + d;
  int l0 = half * 256;
  float sum = 0.f;
#pragma unroll
  for (int j = -12; j <= 12; ++j) {
    int idx = l0 + j;
    idx = idx < 0 ? 0 : idx;
    sum += xb[idx * 512];
  }
#pragma unroll 4
  for (int l = l0; l < l0 + 256; ++l) {
    float xv = xb[l * 512];
    float o = xv - sum * (1.f / 25.f);
    size_t oi = ((size_t)b * 512 + l) * 512 + d;
    outf[oi] = o;
    outb[oi] = f2b(o);
    int ia = l + 13 > 511 ? 511 : l + 13;
    int ir = l - 12 < 0 ? 0 : l - 12;
    sum += xb[ia * 512] - xb[ir * 512];
  }
}

__global__ void k_lnstats(const float* __restrict__ x, float* __restrict__ mu,
                          float* __restrict__ rs)
{
  int row = blockIdx.x;
  const float* xr = x + (size_t)row * 512;
  int t = threadIdx.x;
  float v0 = xr[t], v1 = xr[t + 256];
  float s = v0 + v1, ss = v0 * v0 + v1 * v1;
#pragma unroll
  for (int off = 32; off; off >>= 1) {
    s += __shfl_down(s, off);
    ss += __shfl_down(ss, off);
  }
  __shared__ float as[4], ass[4];
  if ((t & 63) == 0) { as[t >> 6] = s; ass[t >> 6] = ss; }
  __syncthreads();
  if (t == 0) {
    float S = as[0] + as[1] + as[2] + as[3];
    float SS = ass[0] + ass[1] + ass[2] + ass[3];
    float m = S * (1.f / 512.f);
    float var = SS * (1.f / 512.f) - m * m;
    mu[row] = m;
    rs[row] = rsqrtf(var + 1e-5f);
  }
}

// head: cat[b][d] = w_d * (ln_last - mean_l(ln));  norm_b cancels.
__global__ void k_lastcat(const float* __restrict__ x, const float* __restrict__ mu,
                          const float* __restrict__ rs, const float* __restrict__ nw,
                          u16* __restrict__ cat)
{
  int id = blockIdx.x * 256 + threadIdx.x;  // B*D = 32768
  int b = id >> 9, d = id & 511;
  const float* xb = x + (size_t)b * 262144;
  const float* mub = mu + b * 512;
  const float* rsb = rs + b * 512;
  float acc = 0.f;
#pragma unroll 4
  for (int l = 0; l < 512; ++l)
    acc += (xb[l * 512 + d] - mub[l]) * rsb[l];
  float lastv = (xb[511 * 512 + d] - mub[511]) * rsb[511];
  float v = nw[d] * (lastv - acc * (1.f / 512.f));
  cat[b * 544 + d] = f2b(v);
}

__global__ void k_timecat(const float* __restrict__ tv, u16* __restrict__ cat)
{
  int id = blockIdx.x * 256 + threadIdx.x;  // 64*32
  if (id >= 2048) return;
  int b = id >> 5, j = id & 31;
  int pos = 512 + j;
  float v = (pos < 536) ? tv[((size_t)b * 512 + 511) * 24 + (pos - 512)] : 0.f;
  cat[b * 544 + pos] = f2b(v);
}

// ---------------------------------------------------------------------------
extern "C" void kernel_launch(void* const* d_in, const int* in_sizes, int n_in,
                              void* d_out, int out_size, void* d_ws, size_t ws_size,
                              hipStream_t stream)
{
  (void)in_sizes; (void)n_in; (void)out_size; (void)ws_size;
  const int*   x_app  = (const int*)  d_in[0];
  const float* x_time = (const float*)d_in[1];
  const float* tvec   = (const float*)d_in[2];
  // d_in[3] targets: unused by reference output
  const float* emb    = (const float*)d_in[4];
  const float* time_w = (const float*)d_in[5];
  const float* time_b = (const float*)d_in[6];
  const float* Wq     = (const float*)d_in[7];
  const float* bq     = (const float*)d_in[8];
  const float* Wo     = (const float*)d_in[9];
  const float* bo     = (const float*)d_in[10];
  const float* fwr    = (const float*)d_in[11];
  const float* fwi    = (const float*)d_in[12];
  const float* c1     = (const float*)d_in[13];
  const float* c2     = (const float*)d_in[14];
  const float* norm_w = (const float*)d_in[15];
  // d_in[16] norm_b: cancels in (xh - mean_l xh)
  const float* proj_w = (const float*)d_in[17];
  const float* proj_b = (const float*)d_in[18];
  float* out = (float*)d_out;

  char* w = (char*)d_ws;
  auto alloc = [&](size_t bytes) -> char* {
    char* p = w;
    w += (bytes + 255) & ~(size_t)255;
    return p;
  };
  // Workspace budget: ~244 MB (256MiB cap; R3 overflow post-mortem)
  float* Ax   = (float*)alloc(67108864);          // x fp32 (B,L,D)
  float* Bs   = (float*)alloc(67108864);          // t1/t2 fp32
  u16*   Cb   = (u16*)  alloc(33554432);          // bf16 activation
  u16*   YqT  = (u16*)  alloc(33554432);          // qT bf16 (early) / conv1 out (late)
  float* S1   = (float*)alloc(8388608);           // spec (B,64,D) fp32
  u16*   Coef = (u16*)  alloc(4194304);           // mixed spectrum, GEMM-A bf16
  float* wrT  = (float*)alloc(2 * 1048576 * 4);   // mix weights transposed
  float* wiT  = (float*)alloc(2 * 1048576 * 4);
  u16*   wqb  = (u16*)  alloc(2 * 262144 * 2);
  u16*   wob  = (u16*)  alloc(2 * 262144 * 2);
  u16*   c1b  = (u16*)  alloc(2 * 1048576 * 2);
  u16*   c2b  = (u16*)  alloc(2 * 1048576 * 2);
  u16*   pwb  = (u16*)  alloc(10000 * 544 * 2);
  u16*   dftB = (u16*)  alloc(64 * 512 * 2);
  u16*   Binv = (u16*)  alloc(512 * 64 * 2);
  float* muB  = (float*)alloc(131072);
  float* rsB  = (float*)alloc(131072);
  u16*   cat  = (u16*)  alloc(64 * 544 * 2);

  k_basis<<<128, 256, 0, stream>>>(dftB, Binv);
  k_transp<<<1024, 256, 0, stream>>>(fwr, fwi, wrT, wiT);
  k_convert<<<2048, 256, 0, stream>>>(Wq, wqb, 524288);
  k_convert<<<2048, 256, 0, stream>>>(Wo, wob, 524288);
  k_convert<<<8192, 256, 0, stream>>>(c1, c1b, 2097152);
  k_convert<<<8192, 256, 0, stream>>>(c2, c2b, 2097152);
  k_convproj<<<21250, 256, 0, stream>>>(proj_w, pwb);
  k_embed<<<16384, 256, 0, stream>>>(x_app, x_time, emb, time_w, time_b, Ax, Cb);

  for (int l = 0; l < 2; ++l) {
    const u16* wq_l = wqb + l * 262144;
    const u16* wo_l = wob + l * 262144;
    const u16* c1_l = c1b + l * 1048576;
    const u16* c2_l = c2b + l * 1048576;

    // qT[b][d][l] = (x @ Wq^T + bq)^T, bf16, batched over b, TRANS store
    k_gemm<true, false, false, true, false, true, false>
        <<<dim3(4, 4, 64), 256, 0, stream>>>(
        Cb, wq_l, bq + l * 512, nullptr, nullptr, YqT, 512, 512, 512,
        262144, 0, 262144, 0, 0);
    // spec[b][m][d] = qT[b] @ dftB^T  (M=512,N=64 pad 128,K=512), TRANS store
    k_gemm<false, false, false, false, true, true, false>
        <<<dim3(1, 4, 64), 256, 0, stream>>>(
        YqT, dftB, nullptr, nullptr, S1, nullptr, 512, 64, 512,
        262144, 0, 32768, 0, 0);
    k_mix<<<dim3(256, 4), 256, 0, stream>>>(
        S1, wrT + l * 1048576, wiT + l * 1048576, Coef);
    // inverse DFT as GEMM: Cb[b*512+d][l] = Coef @ Binv^T  (M=32768,N=512,K=64)
    k_gemm<false, false, false, true, false, false, true>
        <<<dim3(1024, 1, 1), 256, 0, stream>>>(
        Coef, Binv, nullptr, nullptr, nullptr, Cb, 32768, 512, 64,
        0, 0, 0, 4, 256);
    // t1 = fourier_reshaped @ Wo^T + bo + x
    k_gemm<true, false, true, false, false, false, true>
        <<<dim3(1024, 1, 1), 256, 0, stream>>>(
        Cb, wo_l, bo + l * 512, Ax, Bs, nullptr, 32768, 512, 512,
        0, 0, 0, 4, 256);
    k_decomp<<<256, 256, 0, stream>>>(Bs, Ax, Cb);  // x1 fp32 + bf16
    for (int ch = 0; ch < 4; ++ch) {
      const size_t eo = (size_t)ch * 8192 * 512;
      // y = relu(x1 @ c1^T) -> bf16
      k_gemm<false, true, false, true, false, false, true>
          <<<dim3(1024, 1, 1), 256, 0, stream>>>(
          Cb + eo, c1_l, nullptr, nullptr, nullptr, YqT, 8192, 2048, 512,
          0, 0, 0, 16, 64);
      // t2 = y @ c2^T + x1
      k_gemm<false, false, true, false, false, false, true>
          <<<dim3(256, 1, 1), 256, 0, stream>>>(
          YqT, c2_l, nullptr, Ax + eo, Bs + eo, nullptr, 8192, 512, 2048,
          0, 0, 0, 4, 64);
    }
    k_decomp<<<256, 256, 0, stream>>>(Bs, Ax, Cb);  // next-layer x fp32 + bf16
  }

  k_lnstats<<<32768, 256, 0, stream>>>(Ax, muB, rsB);
  k_lastcat<<<128, 256, 0, stream>>>(Ax, muB, rsB, norm_w, cat);
  k_timecat<<<8, 256, 0, stream>>>(tvec, cat);
  // score = cat @ proj_w^T + proj_b   (K padded 536->544 with zeros)
  k_gemm<true, false, false, false, true, false, false>
      <<<dim3(79, 1, 1), 256, 0, stream>>>(
      cat, pwb, proj_b, nullptr, out, nullptr, 64, 10000, 544,
      0, 0, 0, 0, 0);
}